// Round 11
// baseline (5138.548 us; speedup 1.0000x reference)
//
#include <hip/hip_runtime.h>
#include <hip/hip_bf16.h>
#include <math.h>

typedef __bf16 bf16;
typedef __attribute__((ext_vector_type(8))) __bf16 bf16x8;
typedef __attribute__((ext_vector_type(4))) float f32x4;

#define LDP 40  // padded LDS row (32 + 8) in bf16 elems; keeps 16B alignment, breaks bank conflicts

// ---------------- fp32 -> bf16 bulk convert (per-layer weight prep) ----------------
__global__ __launch_bounds__(256)
void f32_to_bf16(const float* __restrict__ src, bf16* __restrict__ dst, int n8) {
  const int i = blockIdx.x * 256 + threadIdx.x;  // index of 8-elem group
  if (i >= n8) return;
  const f32x4* s = reinterpret_cast<const f32x4*>(src + (size_t)i * 8);
  const f32x4 a = s[0], b = s[1];
  bf16x8 o;
  #pragma unroll
  for (int j = 0; j < 4; ++j) { o[j] = (bf16)a[j]; o[4 + j] = (bf16)b[j]; }
  *reinterpret_cast<bf16x8*>(dst + (size_t)i * 8) = o;
}

// ---------------- input projection + positional embedding ----------------
// h[t*8+b][0:448]  = x[t,b,:] @ W_in + b_in
// h[t*8+b][448+j]  = j<32 ? sin(t*inv[j]) : cos(t*inv[j-32])
__global__ __launch_bounds__(256)
void input_kernel(const float* __restrict__ x, const float* __restrict__ W_in,
                  const float* __restrict__ b_in, float* __restrict__ h,
                  bf16* __restrict__ hb) {
  __shared__ float xs[128];
  const int row = blockIdx.x;  // t*8 + b
  const int tid = threadIdx.x;
  if (tid < 128) xs[tid] = x[(size_t)row * 128 + tid];
  __syncthreads();
  const float tt = (float)(row >> 3);
  for (int n = tid; n < 512; n += 256) {
    float v;
    if (n < 448) {
      float acc = b_in[n];
      #pragma unroll 8
      for (int k = 0; k < 128; ++k) acc = fmaf(xs[k], W_in[(size_t)k * 448 + n], acc);
      v = acc;
    } else {
      const int j = n - 448;
      const int jj = (j < 32) ? j : (j - 32);
      const float inv = __expf((float)jj * (-11.512925464970229f / 31.0f)); // -ln(1e5)/31
      const float a = tt * inv;
      v = (j < 32) ? sinf(a) : cosf(a);
    }
    h[(size_t)row * 512 + n] = v;
    hb[(size_t)row * 512 + n] = (bf16)v;
  }
}

// ---------------- generic GEMM: C = A(bf16, MxK) @ W(bf16, KxN) + bias(f32) ----------------
// MODE: 0 = f32 out, 1 = bf16 out, 2 = bf16 out + relu
template<int MODE>
__global__ __launch_bounds__(256)
void gemm_aw(const bf16* __restrict__ A, const bf16* __restrict__ W,
             const float* __restrict__ bias, void* __restrict__ Cout,
             int M, int N, int K) {
  __shared__ bf16 As[128][LDP];
  __shared__ bf16 Bt[128][LDP];  // Bt[n][k]
  const int tid  = threadIdx.x;
  const int lane = tid & 63;
  const int wid  = tid >> 6;
  const int wm   = (wid >> 1) * 64;
  const int wn   = (wid & 1) * 64;
  const int row0 = blockIdx.y * 128;
  const int col0 = blockIdx.x * 128;
  const int arow = tid >> 2;
  const int acol = (tid & 3) * 8;

  f32x4 acc[4][4] = {};

  for (int k0 = 0; k0 < K; k0 += 32) {
    __syncthreads();
    // stage A tile (128x32 bf16), 8 contiguous elems/thread, two halves
    *reinterpret_cast<bf16x8*>(&As[arow][acol]) =
        *reinterpret_cast<const bf16x8*>(&A[(size_t)(row0 + arow) * K + k0 + acol]);
    *reinterpret_cast<bf16x8*>(&As[64 + arow][acol]) =
        *reinterpret_cast<const bf16x8*>(&A[(size_t)(row0 + 64 + arow) * K + k0 + acol]);
    // stage W tile (32x128 bf16) transposed -> Bt[n][k]
    #pragma unroll
    for (int it = 0; it < 2; ++it) {
      const int idx = (tid + it * 256) * 8;  // 0..4095
      const int kk = idx >> 7;               // 0..31
      const int nn = idx & 127;              // mult of 8
      const bf16x8 wv = *reinterpret_cast<const bf16x8*>(&W[(size_t)(k0 + kk) * N + col0 + nn]);
      #pragma unroll
      for (int j = 0; j < 8; ++j) Bt[nn + j][kk] = wv[j];
    }
    __syncthreads();
    const int fr = lane & 15;
    const int fk = (lane >> 4) * 8;
    bf16x8 af[4], bfr[4];
    #pragma unroll
    for (int m = 0; m < 4; ++m)
      af[m] = *reinterpret_cast<const bf16x8*>(&As[wm + m * 16 + fr][fk]);
    #pragma unroll
    for (int n = 0; n < 4; ++n)
      bfr[n] = *reinterpret_cast<const bf16x8*>(&Bt[wn + n * 16 + fr][fk]);
    #pragma unroll
    for (int m = 0; m < 4; ++m)
      #pragma unroll
      for (int n = 0; n < 4; ++n)
        acc[m][n] = __builtin_amdgcn_mfma_f32_16x16x32_bf16(af[m], bfr[n], acc[m][n], 0, 0, 0);
  }

  const int er = (lane >> 4) * 4;
  const int ec = lane & 15;
  #pragma unroll
  for (int m = 0; m < 4; ++m)
    #pragma unroll
    for (int n = 0; n < 4; ++n) {
      const int gcol = col0 + wn + n * 16 + ec;
      const float bv = bias[gcol];
      #pragma unroll
      for (int rr = 0; rr < 4; ++rr) {
        const int grow = row0 + wm + m * 16 + er + rr;
        float vv = acc[m][n][rr] + bv;
        if (MODE == 2) vv = fmaxf(vv, 0.0f);
        if (MODE == 0) ((float*)Cout)[(size_t)grow * N + gcol] = vv;
        else           ((bf16*)Cout)[(size_t)grow * N + gcol] = (bf16)vv;
      }
    }
}

// ---------------- attention scores: sim[z][t][s] = scale * sum_d Q.K ----------------
__global__ __launch_bounds__(256)
void attn_scores(const bf16* __restrict__ Q, const bf16* __restrict__ Km,
                 float* __restrict__ sim, int bh0, float scale) {
  __shared__ bf16 Qs[128][LDP];
  __shared__ bf16 Ks[128][LDP];
  const int tid = threadIdx.x, lane = tid & 63, wid = tid >> 6;
  const int wm = (wid >> 1) * 64, wn = (wid & 1) * 64;
  const int zz = blockIdx.z;
  const int bh = bh0 + zz;
  const int bb = bh >> 3, hh = bh & 7;
  const size_t base = (size_t)bb * 4096 + (size_t)hh * 512;
  const int t0 = blockIdx.y * 128, s0 = blockIdx.x * 128;
  const int arow = tid >> 2, acol = (tid & 3) * 8;
  f32x4 acc[4][4] = {};
  for (int d0 = 0; d0 < 512; d0 += 32) {
    __syncthreads();
    *reinterpret_cast<bf16x8*>(&Qs[arow][acol]) =
      *reinterpret_cast<const bf16x8*>(&Q[base + (size_t)(t0 + arow) * 32768 + d0 + acol]);
    *reinterpret_cast<bf16x8*>(&Qs[64 + arow][acol]) =
      *reinterpret_cast<const bf16x8*>(&Q[base + (size_t)(t0 + 64 + arow) * 32768 + d0 + acol]);
    *reinterpret_cast<bf16x8*>(&Ks[arow][acol]) =
      *reinterpret_cast<const bf16x8*>(&Km[base + (size_t)(s0 + arow) * 32768 + d0 + acol]);
    *reinterpret_cast<bf16x8*>(&Ks[64 + arow][acol]) =
      *reinterpret_cast<const bf16x8*>(&Km[base + (size_t)(s0 + 64 + arow) * 32768 + d0 + acol]);
    __syncthreads();
    const int fr = lane & 15, fk = (lane >> 4) * 8;
    bf16x8 af[4], bfr[4];
    #pragma unroll
    for (int m = 0; m < 4; ++m)
      af[m] = *reinterpret_cast<const bf16x8*>(&Qs[wm + m * 16 + fr][fk]);
    #pragma unroll
    for (int n = 0; n < 4; ++n)
      bfr[n] = *reinterpret_cast<const bf16x8*>(&Ks[wn + n * 16 + fr][fk]);
    #pragma unroll
    for (int m = 0; m < 4; ++m)
      #pragma unroll
      for (int n = 0; n < 4; ++n)
        acc[m][n] = __builtin_amdgcn_mfma_f32_16x16x32_bf16(af[m], bfr[n], acc[m][n], 0, 0, 0);
  }
  const int er = (lane >> 4) * 4, ec = lane & 15;
  #pragma unroll
  for (int m = 0; m < 4; ++m)
    #pragma unroll
    for (int n = 0; n < 4; ++n)
      #pragma unroll
      for (int rr = 0; rr < 4; ++rr) {
        const int t = t0 + wm + m * 16 + er + rr;
        const int s = s0 + wn + n * 16 + ec;
        sim[((size_t)zz * 512 + t) * 512 + s] = acc[m][n][rr] * scale;
      }
}

// ---------------- row softmax (512 wide), f32 in -> bf16 out ----------------
__global__ __launch_bounds__(256)
void softmax_rows(const float* __restrict__ sim, bf16* __restrict__ P) {
  const int wid = threadIdx.x >> 6, lane = threadIdx.x & 63;
  const size_t row = (size_t)blockIdx.x * 4 + wid;
  const f32x4* rp = reinterpret_cast<const f32x4*>(sim + row * 512);
  const f32x4 a = rp[lane * 2];
  const f32x4 b = rp[lane * 2 + 1];
  float m = a[0];
  #pragma unroll
  for (int j = 1; j < 4; ++j) m = fmaxf(m, a[j]);
  #pragma unroll
  for (int j = 0; j < 4; ++j) m = fmaxf(m, b[j]);
  #pragma unroll
  for (int o = 32; o; o >>= 1) m = fmaxf(m, __shfl_xor(m, o, 64));
  float e[8], s = 0.0f;
  #pragma unroll
  for (int j = 0; j < 4; ++j) { e[j] = __expf(a[j] - m); s += e[j]; }
  #pragma unroll
  for (int j = 0; j < 4; ++j) { e[4 + j] = __expf(b[j] - m); s += e[4 + j]; }
  #pragma unroll
  for (int o = 32; o; o >>= 1) s += __shfl_xor(s, o, 64);
  const float inv = 1.0f / s;
  bf16x8 outv;
  #pragma unroll
  for (int j = 0; j < 8; ++j) outv[j] = (bf16)(e[j] * inv);
  *reinterpret_cast<bf16x8*>(P + row * 512 + lane * 8) = outv;
}

// ---------------- PV: C[(t*8+b)*4096 + h*512 + d] = sum_s P[z][t][s] * V[..] ----------------
__global__ __launch_bounds__(256)
void attn_pv(const bf16* __restrict__ P, const bf16* __restrict__ V,
             bf16* __restrict__ C, int bh0) {
  __shared__ bf16 Ps[128][LDP];
  __shared__ bf16 Vt[128][LDP];  // Vt[d][s]
  const int tid = threadIdx.x, lane = tid & 63, wid = tid >> 6;
  const int wm = (wid >> 1) * 64, wn = (wid & 1) * 64;
  const int zz = blockIdx.z, bh = bh0 + zz;
  const int bb = bh >> 3, hh = bh & 7;
  const size_t vbase = (size_t)bb * 4096 + (size_t)hh * 512;
  const bf16* Pz = P + (size_t)zz * 512 * 512;
  const int t0 = blockIdx.y * 128, d0 = blockIdx.x * 128;
  const int arow = tid >> 2, acol = (tid & 3) * 8;
  f32x4 acc[4][4] = {};
  for (int s0 = 0; s0 < 512; s0 += 32) {
    __syncthreads();
    *reinterpret_cast<bf16x8*>(&Ps[arow][acol]) =
      *reinterpret_cast<const bf16x8*>(&Pz[(size_t)(t0 + arow) * 512 + s0 + acol]);
    *reinterpret_cast<bf16x8*>(&Ps[64 + arow][acol]) =
      *reinterpret_cast<const bf16x8*>(&Pz[(size_t)(t0 + 64 + arow) * 512 + s0 + acol]);
    #pragma unroll
    for (int it = 0; it < 2; ++it) {
      const int idx = (tid + it * 256) * 8;
      const int kk = idx >> 7;   // s-local 0..31
      const int nn = idx & 127;  // d-local, mult of 8
      const bf16x8 vv = *reinterpret_cast<const bf16x8*>(&V[vbase + (size_t)(s0 + kk) * 32768 + d0 + nn]);
      #pragma unroll
      for (int j = 0; j < 8; ++j) Vt[nn + j][kk] = vv[j];
    }
    __syncthreads();
    const int fr = lane & 15, fk = (lane >> 4) * 8;
    bf16x8 af[4], bfr[4];
    #pragma unroll
    for (int m = 0; m < 4; ++m)
      af[m] = *reinterpret_cast<const bf16x8*>(&Ps[wm + m * 16 + fr][fk]);
    #pragma unroll
    for (int n = 0; n < 4; ++n)
      bfr[n] = *reinterpret_cast<const bf16x8*>(&Vt[wn + n * 16 + fr][fk]);
    #pragma unroll
    for (int m = 0; m < 4; ++m)
      #pragma unroll
      for (int n = 0; n < 4; ++n)
        acc[m][n] = __builtin_amdgcn_mfma_f32_16x16x32_bf16(af[m], bfr[n], acc[m][n], 0, 0, 0);
  }
  const int er = (lane >> 4) * 4, ec = lane & 15;
  #pragma unroll
  for (int m = 0; m < 4; ++m)
    #pragma unroll
    for (int n = 0; n < 4; ++n)
      #pragma unroll
      for (int rr = 0; rr < 4; ++rr) {
        const int t = t0 + wm + m * 16 + er + rr;
        const int d = d0 + wn + n * 16 + ec;
        C[((size_t)(t * 8 + bb)) * 4096 + (size_t)hh * 512 + d] = (bf16)acc[m][n][rr];
      }
}

// ---------------- residual add + LayerNorm, writes f32 h and bf16 hb ----------------
__global__ __launch_bounds__(256)
void add_ln(const float* __restrict__ y, const float* __restrict__ hin,
            const float* __restrict__ g, const float* __restrict__ bta,
            float* __restrict__ hout, bf16* __restrict__ hbout) {
  const int wid = threadIdx.x >> 6, lane = threadIdx.x & 63;
  const size_t row = (size_t)blockIdx.x * 4 + wid;
  const f32x4* yp = reinterpret_cast<const f32x4*>(y + row * 512);
  const f32x4* hp = reinterpret_cast<const f32x4*>(hin + row * 512);
  f32x4 v0 = yp[lane * 2] + hp[lane * 2];
  f32x4 v1 = yp[lane * 2 + 1] + hp[lane * 2 + 1];
  float s = 0.0f, s2 = 0.0f;
  #pragma unroll
  for (int j = 0; j < 4; ++j) { s += v0[j] + v1[j]; s2 += v0[j] * v0[j] + v1[j] * v1[j]; }
  #pragma unroll
  for (int o = 32; o; o >>= 1) { s += __shfl_xor(s, o, 64); s2 += __shfl_xor(s2, o, 64); }
  const float mu = s * (1.0f / 512.0f);
  const float var = s2 * (1.0f / 512.0f) - mu * mu;
  const float r = rsqrtf(var + 1e-5f);
  const f32x4* gp = reinterpret_cast<const f32x4*>(g + lane * 8);
  const f32x4* bp = reinterpret_cast<const f32x4*>(bta + lane * 8);
  const f32x4 g0 = gp[0], g1 = gp[1], b0 = bp[0], b1 = bp[1];
  f32x4 o0, o1;
  bf16x8 ob;
  #pragma unroll
  for (int j = 0; j < 4; ++j) {
    o0[j] = (v0[j] - mu) * r * g0[j] + b0[j];
    o1[j] = (v1[j] - mu) * r * g1[j] + b1[j];
    ob[j] = (bf16)o0[j];
    ob[4 + j] = (bf16)o1[j];
  }
  f32x4* op = reinterpret_cast<f32x4*>(hout + row * 512);
  op[lane * 2] = o0;
  op[lane * 2 + 1] = o1;
  *reinterpret_cast<bf16x8*>(hbout + row * 512 + lane * 8) = ob;
}

// ---------------- host launch ----------------
extern "C" void kernel_launch(void* const* d_in, const int* in_sizes, int n_in,
                              void* d_out, int out_size, void* d_ws, size_t ws_size,
                              hipStream_t stream) {
  (void)in_sizes; (void)n_in; (void)out_size; (void)ws_size;
  const float* x    = (const float*)d_in[0];
  const float* W_in = (const float*)d_in[1];
  const float* b_in = (const float*)d_in[2];
  const float* Wq   = (const float*)d_in[3];
  const float* bq   = (const float*)d_in[4];
  const float* Wk   = (const float*)d_in[5];
  const float* bk   = (const float*)d_in[6];
  const float* Wv   = (const float*)d_in[7];
  const float* bv   = (const float*)d_in[8];
  const float* Wo   = (const float*)d_in[9];
  const float* bo   = (const float*)d_in[10];
  const float* ln1g = (const float*)d_in[11];
  const float* ln1b = (const float*)d_in[12];
  const float* W1   = (const float*)d_in[13];
  const float* b1   = (const float*)d_in[14];
  const float* W2   = (const float*)d_in[15];
  const float* b2   = (const float*)d_in[16];
  const float* ln2g = (const float*)d_in[17];
  const float* ln2b = (const float*)d_in[18];

  char* ws = (char*)d_ws;
  float* h    = (float*)(ws + 0);             // 8,388,608 B
  bf16*  hb   = (bf16*) (ws + 8388608);       // 4,194,304 B
  float* y    = (float*)(ws + 12582912);      // 8,388,608 B
  bf16*  q    = (bf16*) (ws + 20971520);      // 33,554,432 B (also FFN mid)
  bf16*  kbuf = (bf16*) (ws + 54525952);      // 33,554,432 B
  bf16*  v    = (bf16*) (ws + 88080384);      // 33,554,432 B
  bf16*  cbuf = (bf16*) (ws + 121634816);     // 33,554,432 B
  float* sim  = (float*)(ws + 155189248);     // 16,777,216 B (16-bh chunk)
  bf16*  p    = (bf16*) (ws + 171966464);     // 8,388,608 B  (16-bh chunk)
  bf16*  mid  = q;                            // FFN intermediate aliases q
  // per-layer bf16 weight staging
  bf16*  wqb  = (bf16*) (ws + 180355072);     // 4,194,304 B
  bf16*  wkb  = (bf16*) (ws + 184549376);     // 4,194,304 B
  bf16*  wvb  = (bf16*) (ws + 188743680);     // 4,194,304 B
  bf16*  wob  = (bf16*) (ws + 192937984);     // 4,194,304 B
  bf16*  w1b  = (bf16*) (ws + 197132288);     // 2,097,152 B
  bf16*  w2b  = (bf16*) (ws + 199229440);     // 2,097,152 B -> end 201,326,592

  const float scale = 0.044194173824159216f;  // 1/sqrt(512)

  input_kernel<<<4096, 256, 0, stream>>>(x, W_in, b_in, h, hb);

  for (int i = 0; i < 6; ++i) {
    const float* bq_i = bq + (size_t)i * 4096;
    const float* bk_i = bk + (size_t)i * 4096;
    const float* bv_i = bv + (size_t)i * 4096;
    const float* bo_i = bo + (size_t)i * 512;
    const float* b1_i = b1 + (size_t)i * 2048;
    const float* b2_i = b2 + (size_t)i * 512;

    // weight prep: fp32 -> bf16 once per layer (memory-bound, ~10 us total)
    f32_to_bf16<<<1024, 256, 0, stream>>>(Wq + (size_t)i * 2097152, wqb, 262144);
    f32_to_bf16<<<1024, 256, 0, stream>>>(Wk + (size_t)i * 2097152, wkb, 262144);
    f32_to_bf16<<<1024, 256, 0, stream>>>(Wv + (size_t)i * 2097152, wvb, 262144);
    f32_to_bf16<<<1024, 256, 0, stream>>>(Wo + (size_t)i * 2097152, wob, 262144);
    f32_to_bf16<<< 512, 256, 0, stream>>>(W1 + (size_t)i * 1048576, w1b, 131072);
    f32_to_bf16<<< 512, 256, 0, stream>>>(W2 + (size_t)i * 1048576, w2b, 131072);

    gemm_aw<1><<<dim3(32, 32), 256, 0, stream>>>(hb, wqb, bq_i, q,    4096, 4096, 512);
    gemm_aw<1><<<dim3(32, 32), 256, 0, stream>>>(hb, wkb, bk_i, kbuf, 4096, 4096, 512);
    gemm_aw<1><<<dim3(32, 32), 256, 0, stream>>>(hb, wvb, bv_i, v,    4096, 4096, 512);

    for (int c = 0; c < 4; ++c) {
      attn_scores<<<dim3(4, 4, 16), 256, 0, stream>>>(q, kbuf, sim, c * 16, scale);
      softmax_rows<<<2048, 256, 0, stream>>>(sim, p);
      attn_pv<<<dim3(4, 4, 16), 256, 0, stream>>>(p, v, cbuf, c * 16);
    }

    gemm_aw<0><<<dim3(4, 32), 256, 0, stream>>>(cbuf, wob, bo_i, y, 4096, 512, 4096);
    add_ln<<<1024, 256, 0, stream>>>(y, h, ln1g + (size_t)i * 512, ln1b + (size_t)i * 512, h, hb);

    gemm_aw<2><<<dim3(16, 32), 256, 0, stream>>>(hb, w1b, b1_i, mid, 4096, 2048, 512);
    gemm_aw<0><<<dim3(4, 32), 256, 0, stream>>>(mid, w2b, b2_i, y, 4096, 512, 2048);
    add_ln<<<1024, 256, 0, stream>>>(y, h, ln2g + (size_t)i * 512, ln2b + (size_t)i * 512, h, hb);
  }

  hipMemcpyAsync(d_out, h, (size_t)4096 * 512 * sizeof(float),
                 hipMemcpyDeviceToDevice, stream);
}